// Round 8
// baseline (669.305 us; speedup 1.0000x reference)
//
#include <hip/hip_runtime.h>
#include <math.h>

#define NN 25000
#define NE 400000
#define HD 64
#define EMBD 8
#define NG 16
#define NC 10
#define SCAN_NB 98   // ceil(NN/256)

// ---------------------------------------------------------------------------
// Sort phase: dst-CSR (edge structure is layer-invariant).
// hist also builds the per-graph node counts (needed by pooled-BN algebra).
// ---------------------------------------------------------------------------
__global__ __launch_bounds__(256) void hist_k(const int* __restrict__ dst,
        const int* __restrict__ gids, int* cnt, int* gcnt) {
    int e = blockIdx.x * 256 + threadIdx.x;
    if (e < NE) atomicAdd(&cnt[dst[e]], 1);
    if (e < NN) atomicAdd(&gcnt[gids[e]], 1);
}

__global__ __launch_bounds__(256) void scan_part_k(const int* __restrict__ cnt, int* bsum) {
    __shared__ int sh[256];
    int tx = threadIdx.x;
    int i = blockIdx.x * 256 + tx;
    sh[tx] = (i < NN) ? cnt[i] : 0;
    __syncthreads();
    for (int off = 128; off > 0; off >>= 1) {
        if (tx < off) sh[tx] += sh[tx + off];
        __syncthreads();
    }
    if (tx == 0) bsum[blockIdx.x] = sh[0];
}

__global__ __launch_bounds__(128) void scan_mid_k(const int* __restrict__ bsum,
        int* boff, int* dstoff) {
    __shared__ int sh[128];
    int tx = threadIdx.x;
    int v = (tx < SCAN_NB) ? bsum[tx] : 0;
    sh[tx] = v;
    __syncthreads();
    for (int off = 1; off < 128; off <<= 1) {
        int t = (tx >= off) ? sh[tx - off] : 0;
        __syncthreads();
        sh[tx] += t;
        __syncthreads();
    }
    if (tx < SCAN_NB) boff[tx] = sh[tx] - v;
    if (tx == 0) dstoff[NN] = NE;
}

__global__ __launch_bounds__(256) void scan_final_k(const int* __restrict__ cnt,
        const int* __restrict__ boff, int* dstoff, int* cur) {
    __shared__ int sh[256];
    int tx = threadIdx.x;
    int i = blockIdx.x * 256 + tx;
    int v = (i < NN) ? cnt[i] : 0;
    sh[tx] = v;
    __syncthreads();
    for (int off = 1; off < 256; off <<= 1) {
        int t = (tx >= off) ? sh[tx - off] : 0;
        __syncthreads();
        sh[tx] += t;
        __syncthreads();
    }
    int excl = boff[blockIdx.x] + sh[tx] - v;
    if (i < NN) { dstoff[i] = excl; cur[i] = excl; }
}

// scatter: place src at dst-sorted slot AND precompute normalized direction.
__global__ __launch_bounds__(256) void scatter_k(const int* __restrict__ src,
        const int* __restrict__ dst, const float* __restrict__ c,
        int* cur, int* __restrict__ src_d, float* __restrict__ dnorm_d) {
    int e = blockIdx.x * 256 + threadIdx.x;
    if (e >= NE) return;
    int s = src[e], t = dst[e];
    int pd = atomicAdd(&cur[t], 1);
    src_d[pd] = s;
    float4 sa = *(const float4*)(c + (size_t)s * 8);
    float4 sb = *(const float4*)(c + (size_t)s * 8 + 4);
    float4 na = *(const float4*)(c + (size_t)t * 8);
    float4 nb = *(const float4*)(c + (size_t)t * 8 + 4);
    float d0 = sa.x - na.x, d1 = sa.y - na.y, d2 = sa.z - na.z, d3 = sa.w - na.w;
    float d4 = sb.x - nb.x, d5 = sb.y - nb.y, d6 = sb.z - nb.z, d7 = sb.w - nb.w;
    float nn2 = d0*d0 + d1*d1 + d2*d2 + d3*d3 + d4*d4 + d5*d5 + d6*d6 + d7*d7;
    float inv = 1.f / fmaxf(sqrtf(nn2), 1e-12f);
    *(float4*)(dnorm_d + (size_t)pd * 8)     = make_float4(d0*inv, d1*inv, d2*inv, d3*inv);
    *(float4*)(dnorm_d + (size_t)pd * 8 + 4) = make_float4(d4*inv, d5*inv, d6*inv, d7*inv);
}

// ---------------------------------------------------------------------------
// K1: E[t, i*64+j] = sum_{e->t} dnorm[e,i] * h[src_e, j]
// Wave-cooperative src prefetch: one coalesced load grabs 64 indices, __shfl
// extracts them (no load on the critical path). Masked 8-wide batches put
// 8 independent h-gathers in flight.
// Block 0 also zeroes sums/sumsq/Xg (layout: contiguous 1152 floats).
// ---------------------------------------------------------------------------
#define NWE 8192
__global__ __launch_bounds__(256) void edge_E_k(const int* __restrict__ src_d,
        const int* __restrict__ dstoff, const float* __restrict__ dnorm_d,
        const float* __restrict__ h, float* __restrict__ E,
        float* __restrict__ stats_zero) {
    if (blockIdx.x == 0) {
        for (int t = threadIdx.x; t < 64 + 64 + NG * 64; t += 256)
            stats_zero[t] = 0.f;
    }
    int gid  = blockIdx.x * 256 + threadIdx.x;
    int w    = gid >> 6;
    int lane = threadIdx.x & 63;
    long long t0 = (long long)w * NE / NWE;
    long long t1 = (long long)(w + 1) * NE / NWE;
    int lo = 0, hi = NN;
    while (lo < hi) { int mid = (lo + hi) >> 1; if (dstoff[mid] < t0) lo = mid + 1; else hi = mid; }
    int nlo = lo;
    lo = 0; hi = NN;
    while (lo < hi) { int mid = (lo + hi) >> 1; if (dstoff[mid] < t1) lo = mid + 1; else hi = mid; }
    int nhi = (w == NWE - 1) ? NN : lo;

    int wbase = -1000000;
    int sidx = 0;
    for (int n = nlo; n < nhi; n++) {
        float e0=0,e1=0,e2=0,e3=0,e4=0,e5=0,e6=0,e7=0;
        int p0 = dstoff[n], p1 = dstoff[n + 1];
        int p = p0;
        while (p < p1) {
            if (p - wbase > 56) {   // guarantee 8 indices available in window
                wbase = p;
                int ld = wbase + lane;
                if (ld > NE - 1) ld = NE - 1;
                sidx = src_d[ld];
            }
            int m = p1 - p; if (m > 8) m = 8;
            int sj[8]; float hj[8];
#pragma unroll
            for (int j = 0; j < 8; j++) sj[j] = __shfl(sidx, p + j - wbase);
#pragma unroll
            for (int j = 0; j < 8; j++)
                if (j < m) hj[j] = h[(size_t)sj[j] * 64 + lane];
#pragma unroll
            for (int j = 0; j < 8; j++)
                if (j < m) {
                    float4 dA = *(const float4*)(dnorm_d + (size_t)(p + j) * 8);
                    float4 dB = *(const float4*)(dnorm_d + (size_t)(p + j) * 8 + 4);
                    float hv = hj[j];
                    e0 = fmaf(dA.x, hv, e0); e1 = fmaf(dA.y, hv, e1);
                    e2 = fmaf(dA.z, hv, e2); e3 = fmaf(dA.w, hv, e3);
                    e4 = fmaf(dB.x, hv, e4); e5 = fmaf(dB.y, hv, e5);
                    e6 = fmaf(dB.z, hv, e6); e7 = fmaf(dB.w, hv, e7);
                }
            p += m;
        }
        float* ep = E + (size_t)n * 512 + lane;
        ep[0*64] = e0; ep[1*64] = e1; ep[2*64] = e2; ep[3*64] = e3;
        ep[4*64] = e4; ep[5*64] = e5; ep[6*64] = e6; ep[7*64] = e7;
    }
}

// ---------------------------------------------------------------------------
// K2: K-split finish GEMM (4 parts of K=128).
// ---------------------------------------------------------------------------
__global__ __launch_bounds__(256) void finish_gemm_part_k(const float* __restrict__ E,
        const float* __restrict__ W, float* __restrict__ P) {
    __shared__ float Et[64][68];
    __shared__ float Wsh[64][64];
    int n0 = blockIdx.x * 64;
    int part = blockIdx.y;
    int tx = threadIdx.x;
    int col0 = (tx & 15) * 4;
    int row0 = (tx >> 4) * 4;
    float acc[4][4] = {{0.f}};

    for (int c = 0; c < 2; c++) {
        __syncthreads();
        for (int t = tx; t < 4096; t += 256) {
            int r = t >> 6, q = t & 63;
            int n = n0 + r;
            Et[q][r] = (n < NN) ? E[(size_t)n * 512 + part * 128 + c * 64 + q] : 0.f;
        }
        for (int t = tx; t < 4096; t += 256)
            Wsh[t >> 6][t & 63] = W[(part * 2 + c) * 4096 + t];
        __syncthreads();
#pragma unroll 8
        for (int q = 0; q < 64; q++) {
            float4 a = *(const float4*)&Et[q][row0];
            float4 b = *(const float4*)&Wsh[q][col0];
            float a4[4] = {a.x, a.y, a.z, a.w};
            float b4[4] = {b.x, b.y, b.z, b.w};
#pragma unroll
            for (int r = 0; r < 4; r++)
#pragma unroll
                for (int cc = 0; cc < 4; cc++)
                    acc[r][cc] = fmaf(a4[r], b4[cc], acc[r][cc]);
        }
    }
    float* Pp = P + (size_t)part * NN * 64;
#pragma unroll
    for (int r = 0; r < 4; r++) {
        int n = n0 + row0 + r;
        if (n < NN)
            *(float4*)(Pp + (size_t)n * 64 + col0) =
                make_float4(acc[r][0], acc[r][1], acc[r][2], acc[r][3]);
    }
}

// ---------------------------------------------------------------------------
// K3: combine 4 partials -> agg; fused relu BN-stats (global sums/sumsq)
// AND per-graph relu sums Xg[g,k] (for the pooled-BN classifier algebra).
// ---------------------------------------------------------------------------
__global__ __launch_bounds__(256) void combine_stats_k(const float* __restrict__ P,
        const int* __restrict__ gids, float* __restrict__ agg,
        float* sums, float* sumsq, float* Xg) {
    __shared__ float pl[NG * 64];
    __shared__ float r1[16 * 64], r2[16 * 64];
    int tx = threadIdx.x;
    for (int t = tx; t < NG * 64; t += 256) pl[t] = 0.f;
    __syncthreads();
    int idx0 = blockIdx.x * 256 + tx;
    int stride = gridDim.x * 256;
    const int n4 = NN * 16;
    int col0 = (tx & 15) * 4;
    float s1v[4] = {0.f}, s2v[4] = {0.f};
    for (int i4 = idx0; i4 < n4; i4 += stride) {
        int n = i4 >> 4;
        int g = gids[n];
        int cl = (i4 & 15) * 4;
        float4 a = *(const float4*)(P + (size_t)i4 * 4);
        float4 b = *(const float4*)(P + (size_t)NN * 64 + (size_t)i4 * 4);
        float4 c = *(const float4*)(P + (size_t)2 * NN * 64 + (size_t)i4 * 4);
        float4 d = *(const float4*)(P + (size_t)3 * NN * 64 + (size_t)i4 * 4);
        float4 v = make_float4(a.x + b.x + c.x + d.x, a.y + b.y + c.y + d.y,
                               a.z + b.z + c.z + d.z, a.w + b.w + c.w + d.w);
        *(float4*)(agg + (size_t)i4 * 4) = v;
        float x0 = fmaxf(v.x, 0.f), x1 = fmaxf(v.y, 0.f);
        float x2 = fmaxf(v.z, 0.f), x3 = fmaxf(v.w, 0.f);
        s1v[0] += x0; s2v[0] += x0 * x0;
        s1v[1] += x1; s2v[1] += x1 * x1;
        s1v[2] += x2; s2v[2] += x2 * x2;
        s1v[3] += x3; s2v[3] += x3 * x3;
        atomicAdd(&pl[g * 64 + cl + 0], x0);
        atomicAdd(&pl[g * 64 + cl + 1], x1);
        atomicAdd(&pl[g * 64 + cl + 2], x2);
        atomicAdd(&pl[g * 64 + cl + 3], x3);
    }
    int grp = tx >> 4;
#pragma unroll
    for (int c = 0; c < 4; c++) {
        r1[grp * 64 + col0 + c] = s1v[c];
        r2[grp * 64 + col0 + c] = s2v[c];
    }
    __syncthreads();
    if (tx < 64) {
        float a = 0.f, b = 0.f;
#pragma unroll
        for (int g = 0; g < 16; g++) { a += r1[g * 64 + tx]; b += r2[g * 64 + tx]; }
        atomicAdd(&sums[tx], a);
        atomicAdd(&sumsq[tx], b);
    }
    __syncthreads();
    for (int t = tx; t < NG * 64; t += 256) {
        float v = pl[t];
        if (v != 0.f) atomicAdd(&Xg[t], v);
    }
}

// ---------------------------------------------------------------------------
// Classifier on pooled features via the pooled-BN identity:
//   pooled(h_new)[g,k] = gamma_k*r_k*(Xg[g,k] - c_g*mu_k) + c_g*beta_k
//                        + sc*pooled(h_old)[g,k]
// 256-thread body; writes P_new back to Pold for the next layer.
// ---------------------------------------------------------------------------
__device__ __forceinline__ void classifier_body(int tx,
        const float* __restrict__ sums, const float* __restrict__ sumsq,
        const float* __restrict__ Xg, const int* __restrict__ gcnt,
        float* __restrict__ Pold,
        const float* __restrict__ gamma, const float* __restrict__ beta,
        const float* __restrict__ cW1, const float* __restrict__ cb1,
        const float* __restrict__ cg1, const float* __restrict__ cbt1,
        const float* __restrict__ cW2, const float* __restrict__ cb2,
        float* __restrict__ logits, int sc) {
    __shared__ float Pn[NG * 64];
    __shared__ float H1s[NG * 32];
    __shared__ float cmu[32], crs[32];
    for (int t = tx; t < NG * 64; t += 256) {
        int g = t >> 6, k = t & 63;
        float mean = sums[k] * (1.f / NN);
        float var  = sumsq[k] * (1.f / NN) - mean * mean;
        float r = rsqrtf(var + 1e-5f);
        float cg = (float)gcnt[g];
        float v = gamma[k] * r * (Xg[t] - cg * mean) + cg * beta[k];
        if (sc) v += Pold[t];
        Pn[t] = v;
        Pold[t] = v;
    }
    __syncthreads();
    for (int t = tx; t < NG * 32; t += 256) {
        int g = t >> 5, c = t & 31;
        float acc = cb1[c];
#pragma unroll 16
        for (int j = 0; j < 64; j++) acc = fmaf(Pn[g * 64 + j], cW1[j * 32 + c], acc);
        H1s[t] = acc;
    }
    __syncthreads();
    if (tx < 32) {
        float mu = 0.f;
#pragma unroll
        for (int g2 = 0; g2 < NG; g2++) mu += H1s[g2 * 32 + tx];
        mu *= (1.f / NG);
        float v = 0.f;
#pragma unroll
        for (int g2 = 0; g2 < NG; g2++) {
            float d = H1s[g2 * 32 + tx] - mu;
            v += d * d;
        }
        v *= (1.f / NG);
        cmu[tx] = mu;
        crs[tx] = rsqrtf(v + 1e-5f);
    }
    __syncthreads();
    for (int t = tx; t < NG * 32; t += 256) {
        int c = t & 31;
        H1s[t] = fmaxf(cg1[c] * (H1s[t] - cmu[c]) * crs[c] + cbt1[c], 0.f);
    }
    __syncthreads();
    if (tx < NG * NC) {
        int g = tx / NC, cls = tx % NC;
        float a2 = cb2[cls];
#pragma unroll
        for (int j = 0; j < 32; j++) a2 = fmaf(H1s[g * 32 + j], cW2[j * NC + cls], a2);
        logits[tx] += a2;
    }
}

// ---------------------------------------------------------------------------
// K4: BN apply + shortcut -> h_new; block 0 additionally runs the classifier
// (it depends only on combine's outputs, so it overlaps with the BN sweep).
// ---------------------------------------------------------------------------
__global__ __launch_bounds__(256) void bn_apply_k(const float* __restrict__ agg,
        const float* __restrict__ h_old, const float* __restrict__ sums,
        const float* __restrict__ sumsq, const float* __restrict__ gamma,
        const float* __restrict__ beta, float* __restrict__ h_new, int shortcut,
        const float* __restrict__ Xg, const int* __restrict__ gcnt,
        float* __restrict__ Pold,
        const float* __restrict__ cW1, const float* __restrict__ cb1,
        const float* __restrict__ cg1, const float* __restrict__ cbt1,
        const float* __restrict__ cW2, const float* __restrict__ cb2,
        float* __restrict__ logits) {
    int tx = threadIdx.x;
    int k = tx & 63;
    float mean = sums[k] * (1.f / NN);
    float var  = sumsq[k] * (1.f / NN) - mean * mean;
    float rstd = rsqrtf(var + 1e-5f);
    float g = gamma[k], b = beta[k];
    int idx0 = blockIdx.x * 256 + tx;
    int stride = gridDim.x * 256;
    for (int idx = idx0; idx < NN * 64; idx += stride) {
        float x = fmaxf(agg[idx], 0.f);
        float y = g * (x - mean) * rstd + b;
        if (shortcut) y += h_old[idx];
        h_new[idx] = y;
    }
    if (blockIdx.x == 0)
        classifier_body(tx, sums, sumsq, Xg, gcnt, Pold, gamma, beta,
                        cW1, cb1, cg1, cbt1, cW2, cb2, logits, shortcut);
}

// Layer 2: h_new is never consumed -> classifier only (1 block).
__global__ __launch_bounds__(256) void classifier_only_k(
        const float* __restrict__ sums, const float* __restrict__ sumsq,
        const float* __restrict__ Xg, const int* __restrict__ gcnt,
        float* __restrict__ Pold,
        const float* __restrict__ gamma, const float* __restrict__ beta,
        const float* __restrict__ cW1, const float* __restrict__ cb1,
        const float* __restrict__ cg1, const float* __restrict__ cbt1,
        const float* __restrict__ cW2, const float* __restrict__ cb2,
        float* __restrict__ logits) {
    classifier_body(threadIdx.x, sums, sumsq, Xg, gcnt, Pold, gamma, beta,
                    cW1, cb1, cg1, cbt1, cW2, cb2, logits, 1);
}

// ---------------------------------------------------------------------------
extern "C" void kernel_launch(void* const* d_in, const int* in_sizes, int n_in,
                              void* d_out, int out_size, void* d_ws, size_t ws_size,
                              hipStream_t stream) {
    const float* feature = (const float*)d_in[0];
    const float* cemb    = (const float*)d_in[1];
    const int*   src     = (const int*)d_in[2];
    const int*   dst     = (const int*)d_in[3];
    const int*   gids    = (const int*)d_in[4];
    const float* W[3]    = {(const float*)d_in[5], (const float*)d_in[6], (const float*)d_in[7]};
    const float* gam[3]  = {(const float*)d_in[8], (const float*)d_in[10], (const float*)d_in[12]};
    const float* bet[3]  = {(const float*)d_in[9], (const float*)d_in[11], (const float*)d_in[13]};
    const float* cW1  = (const float*)d_in[14];
    const float* cb1  = (const float*)d_in[15];
    const float* cg1  = (const float*)d_in[16];
    const float* cbt1 = (const float*)d_in[17];
    const float* cW2  = (const float*)d_in[18];
    const float* cb2  = (const float*)d_in[19];
    float* out = (float*)d_out;

    // workspace layout (4-byte units)
    float* ws      = (float*)d_ws;
    float* E       = ws;                           // NN*512  = 12,800,000
    float* Pparts  = E + (size_t)NN * 512;         // 4*NN*64 = 6,400,000
    float* dnorm_d = Pparts + (size_t)4 * NN * 64; // NE*8    = 3,200,000
    float* bufX    = dnorm_d + (size_t)NE * 8;     // NN*64
    float* bufY    = bufX + (size_t)NN * 64;       // NN*64
    float* sums    = bufY + (size_t)NN * 64;       // 64   } contiguous 1152
    float* sumsq   = sums + 64;                    // 64   } zeroed by edge_E
    float* Xg      = sumsq + 64;                   // 1024 } block 0
    float* Pold    = Xg + 1024;                    // 1024 (persists across layers)
    int*   cnt     = (int*)(Pold + 1024);          // NN   } contiguous memset
    int*   gcnt    = cnt + NN;                     // 16   }
    int*   cur     = gcnt + 16;                    // NN
    int*   dstoff  = cur + NN;                     // NN+1 (pad +8)
    int*   bsum    = dstoff + NN + 8;              // 128
    int*   boff    = bsum + 128;                   // 128
    int*   src_d   = boff + 128;                   // NE

    hipMemsetAsync(d_out, 0, (size_t)NG * NC * sizeof(float), stream);
    hipMemsetAsync(cnt, 0, (NN + 16) * sizeof(int), stream);

    hist_k<<<(NE + 255) / 256, 256, 0, stream>>>(dst, gids, cnt, gcnt);
    scan_part_k<<<SCAN_NB, 256, 0, stream>>>(cnt, bsum);
    scan_mid_k<<<1, 128, 0, stream>>>(bsum, boff, dstoff);
    scan_final_k<<<SCAN_NB, 256, 0, stream>>>(cnt, boff, dstoff, cur);
    scatter_k<<<(NE + 255) / 256, 256, 0, stream>>>(src, dst, cemb, cur, src_d, dnorm_d);

    const float* h_old = feature;
    float* bufs[2] = {bufX, bufY};
    for (int l = 0; l < 3; l++) {
        float* agg = bufs[l & 1];
        edge_E_k<<<NWE / 4, 256, 0, stream>>>(src_d, dstoff, dnorm_d, h_old, E, sums);
        finish_gemm_part_k<<<dim3((NN + 63) / 64, 4), 256, 0, stream>>>(E, W[l], Pparts);
        combine_stats_k<<<512, 256, 0, stream>>>(Pparts, gids, agg, sums, sumsq, Xg);
        if (l < 2) {
            bn_apply_k<<<256, 256, 0, stream>>>(agg, h_old, sums, sumsq, gam[l], bet[l],
                                                agg, l > 0, Xg, gcnt, Pold,
                                                cW1, cb1, cg1, cbt1, cW2, cb2, out);
        } else {
            classifier_only_k<<<1, 256, 0, stream>>>(sums, sumsq, Xg, gcnt, Pold,
                                                     gam[l], bet[l],
                                                     cW1, cb1, cg1, cbt1, cW2, cb2, out);
        }
        h_old = agg;
    }
}

// Round 9
// 533.921 us; speedup vs baseline: 1.2536x; 1.2536x over previous
//
#include <hip/hip_runtime.h>
#include <math.h>

#define NN 25000
#define NE 400000
#define HD 64
#define EMBD 8
#define NG 16
#define NC 10
#define SCAN_NB 98   // ceil(NN/256)

// ---------------------------------------------------------------------------
// Sort phase: dst-CSR (edge structure is layer-invariant).
// ---------------------------------------------------------------------------
__global__ __launch_bounds__(256) void hist_k(const int* __restrict__ dst, int* cnt) {
    int e = blockIdx.x * 256 + threadIdx.x;
    if (e < NE) atomicAdd(&cnt[dst[e]], 1);
}

__global__ __launch_bounds__(256) void scan_part_k(const int* __restrict__ cnt, int* bsum) {
    __shared__ int sh[256];
    int tx = threadIdx.x;
    int i = blockIdx.x * 256 + tx;
    sh[tx] = (i < NN) ? cnt[i] : 0;
    __syncthreads();
    for (int off = 128; off > 0; off >>= 1) {
        if (tx < off) sh[tx] += sh[tx + off];
        __syncthreads();
    }
    if (tx == 0) bsum[blockIdx.x] = sh[0];
}

// single small block: scan of block sums; ALSO computes gcnt[g] by binary
// search over the (sorted) graph_ids — no atomics (sorted ids would cause
// worst-case same-bin atomic serialization, measured 175us in R8).
__global__ __launch_bounds__(128) void scan_mid_k(const int* __restrict__ bsum,
        int* boff, int* dstoff, const int* __restrict__ gids, int* gcnt) {
    __shared__ int sh[128];
    int tx = threadIdx.x;
    int v = (tx < SCAN_NB) ? bsum[tx] : 0;
    sh[tx] = v;
    __syncthreads();
    for (int off = 1; off < 128; off <<= 1) {
        int t = (tx >= off) ? sh[tx - off] : 0;
        __syncthreads();
        sh[tx] += t;
        __syncthreads();
    }
    if (tx < SCAN_NB) boff[tx] = sh[tx] - v;
    if (tx == 0) dstoff[NN] = NE;
    if (tx < NG) {
        // lower_bound(tx) and lower_bound(tx+1) over sorted gids
        int lo = 0, hi = NN;
        while (lo < hi) { int m = (lo + hi) >> 1; if (gids[m] < tx) lo = m + 1; else hi = m; }
        int a = lo;
        lo = 0; hi = NN;
        while (lo < hi) { int m = (lo + hi) >> 1; if (gids[m] < tx + 1) lo = m + 1; else hi = m; }
        gcnt[tx] = lo - a;
    }
}

__global__ __launch_bounds__(256) void scan_final_k(const int* __restrict__ cnt,
        const int* __restrict__ boff, int* dstoff, int* cur) {
    __shared__ int sh[256];
    int tx = threadIdx.x;
    int i = blockIdx.x * 256 + tx;
    int v = (i < NN) ? cnt[i] : 0;
    sh[tx] = v;
    __syncthreads();
    for (int off = 1; off < 256; off <<= 1) {
        int t = (tx >= off) ? sh[tx - off] : 0;
        __syncthreads();
        sh[tx] += t;
        __syncthreads();
    }
    int excl = boff[blockIdx.x] + sh[tx] - v;
    if (i < NN) { dstoff[i] = excl; cur[i] = excl; }
}

// scatter: place src at dst-sorted slot AND precompute normalized direction.
__global__ __launch_bounds__(256) void scatter_k(const int* __restrict__ src,
        const int* __restrict__ dst, const float* __restrict__ c,
        int* cur, int* __restrict__ src_d, float* __restrict__ dnorm_d) {
    int e = blockIdx.x * 256 + threadIdx.x;
    if (e >= NE) return;
    int s = src[e], t = dst[e];
    int pd = atomicAdd(&cur[t], 1);
    src_d[pd] = s;
    float4 sa = *(const float4*)(c + (size_t)s * 8);
    float4 sb = *(const float4*)(c + (size_t)s * 8 + 4);
    float4 na = *(const float4*)(c + (size_t)t * 8);
    float4 nb = *(const float4*)(c + (size_t)t * 8 + 4);
    float d0 = sa.x - na.x, d1 = sa.y - na.y, d2 = sa.z - na.z, d3 = sa.w - na.w;
    float d4 = sb.x - nb.x, d5 = sb.y - nb.y, d6 = sb.z - nb.z, d7 = sb.w - nb.w;
    float nn2 = d0*d0 + d1*d1 + d2*d2 + d3*d3 + d4*d4 + d5*d5 + d6*d6 + d7*d7;
    float inv = 1.f / fmaxf(sqrtf(nn2), 1e-12f);
    *(float4*)(dnorm_d + (size_t)pd * 8)     = make_float4(d0*inv, d1*inv, d2*inv, d3*inv);
    *(float4*)(dnorm_d + (size_t)pd * 8 + 4) = make_float4(d4*inv, d5*inv, d6*inv, d7*inv);
}

// ---------------------------------------------------------------------------
// K1: E[t, i*64+j] = sum_{e->t} dnorm[e,i] * h[src_e, j]
// Wave-cooperative src prefetch (coalesced 64-index load + __shfl extract),
// masked 8-wide gather batches. Block 0 zeroes the stats block.
// ---------------------------------------------------------------------------
#define NWE 8192
__global__ __launch_bounds__(256) void edge_E_k(const int* __restrict__ src_d,
        const int* __restrict__ dstoff, const float* __restrict__ dnorm_d,
        const float* __restrict__ h, float* __restrict__ E,
        float* __restrict__ stats_zero) {
    if (blockIdx.x == 0) {
        for (int t = threadIdx.x; t < 64 + 64 + NG * 64; t += 256)
            stats_zero[t] = 0.f;
    }
    int gid  = blockIdx.x * 256 + threadIdx.x;
    int w    = gid >> 6;
    int lane = threadIdx.x & 63;
    long long t0 = (long long)w * NE / NWE;
    long long t1 = (long long)(w + 1) * NE / NWE;
    int lo = 0, hi = NN;
    while (lo < hi) { int mid = (lo + hi) >> 1; if (dstoff[mid] < t0) lo = mid + 1; else hi = mid; }
    int nlo = lo;
    lo = 0; hi = NN;
    while (lo < hi) { int mid = (lo + hi) >> 1; if (dstoff[mid] < t1) lo = mid + 1; else hi = mid; }
    int nhi = (w == NWE - 1) ? NN : lo;

    int wbase = -1000000;
    int sidx = 0;
    for (int n = nlo; n < nhi; n++) {
        float e0=0,e1=0,e2=0,e3=0,e4=0,e5=0,e6=0,e7=0;
        int p0 = dstoff[n], p1 = dstoff[n + 1];
        int p = p0;
        while (p < p1) {
            if (p - wbase > 56) {   // guarantee 8 indices available in window
                wbase = p;
                int ld = wbase + lane;
                if (ld > NE - 1) ld = NE - 1;
                sidx = src_d[ld];
            }
            int m = p1 - p; if (m > 8) m = 8;
            int sj[8]; float hj[8];
#pragma unroll
            for (int j = 0; j < 8; j++) sj[j] = __shfl(sidx, p + j - wbase);
#pragma unroll
            for (int j = 0; j < 8; j++)
                if (j < m) hj[j] = h[(size_t)sj[j] * 64 + lane];
#pragma unroll
            for (int j = 0; j < 8; j++)
                if (j < m) {
                    float4 dA = *(const float4*)(dnorm_d + (size_t)(p + j) * 8);
                    float4 dB = *(const float4*)(dnorm_d + (size_t)(p + j) * 8 + 4);
                    float hv = hj[j];
                    e0 = fmaf(dA.x, hv, e0); e1 = fmaf(dA.y, hv, e1);
                    e2 = fmaf(dA.z, hv, e2); e3 = fmaf(dA.w, hv, e3);
                    e4 = fmaf(dB.x, hv, e4); e5 = fmaf(dB.y, hv, e5);
                    e6 = fmaf(dB.z, hv, e6); e7 = fmaf(dB.w, hv, e7);
                }
            p += m;
        }
        float* ep = E + (size_t)n * 512 + lane;
        ep[0*64] = e0; ep[1*64] = e1; ep[2*64] = e2; ep[3*64] = e3;
        ep[4*64] = e4; ep[5*64] = e5; ep[6*64] = e6; ep[7*64] = e7;
    }
}

// ---------------------------------------------------------------------------
// K2: K-split finish GEMM (4 parts of K=128).
// ---------------------------------------------------------------------------
__global__ __launch_bounds__(256) void finish_gemm_part_k(const float* __restrict__ E,
        const float* __restrict__ W, float* __restrict__ P) {
    __shared__ float Et[64][68];
    __shared__ float Wsh[64][64];
    int n0 = blockIdx.x * 64;
    int part = blockIdx.y;
    int tx = threadIdx.x;
    int col0 = (tx & 15) * 4;
    int row0 = (tx >> 4) * 4;
    float acc[4][4] = {{0.f}};

    for (int c = 0; c < 2; c++) {
        __syncthreads();
        for (int t = tx; t < 4096; t += 256) {
            int r = t >> 6, q = t & 63;
            int n = n0 + r;
            Et[q][r] = (n < NN) ? E[(size_t)n * 512 + part * 128 + c * 64 + q] : 0.f;
        }
        for (int t = tx; t < 4096; t += 256)
            Wsh[t >> 6][t & 63] = W[(part * 2 + c) * 4096 + t];
        __syncthreads();
#pragma unroll 8
        for (int q = 0; q < 64; q++) {
            float4 a = *(const float4*)&Et[q][row0];
            float4 b = *(const float4*)&Wsh[q][col0];
            float a4[4] = {a.x, a.y, a.z, a.w};
            float b4[4] = {b.x, b.y, b.z, b.w};
#pragma unroll
            for (int r = 0; r < 4; r++)
#pragma unroll
                for (int cc = 0; cc < 4; cc++)
                    acc[r][cc] = fmaf(a4[r], b4[cc], acc[r][cc]);
        }
    }
    float* Pp = P + (size_t)part * NN * 64;
#pragma unroll
    for (int r = 0; r < 4; r++) {
        int n = n0 + row0 + r;
        if (n < NN)
            *(float4*)(Pp + (size_t)n * 64 + col0) =
                make_float4(acc[r][0], acc[r][1], acc[r][2], acc[r][3]);
    }
}

// ---------------------------------------------------------------------------
// K3: combine 4 partials -> agg; fused relu BN-stats (global sums/sumsq)
// AND per-graph relu sums Xg[g,k] (for the pooled-BN classifier algebra).
// ---------------------------------------------------------------------------
__global__ __launch_bounds__(256) void combine_stats_k(const float* __restrict__ P,
        const int* __restrict__ gids, float* __restrict__ agg,
        float* sums, float* sumsq, float* Xg) {
    __shared__ float pl[NG * 64];
    __shared__ float r1[16 * 64], r2[16 * 64];
    int tx = threadIdx.x;
    for (int t = tx; t < NG * 64; t += 256) pl[t] = 0.f;
    __syncthreads();
    int idx0 = blockIdx.x * 256 + tx;
    int stride = gridDim.x * 256;
    const int n4 = NN * 16;
    int col0 = (tx & 15) * 4;
    float s1v[4] = {0.f}, s2v[4] = {0.f};
    for (int i4 = idx0; i4 < n4; i4 += stride) {
        int n = i4 >> 4;
        int g = gids[n];
        int cl = (i4 & 15) * 4;
        float4 a = *(const float4*)(P + (size_t)i4 * 4);
        float4 b = *(const float4*)(P + (size_t)NN * 64 + (size_t)i4 * 4);
        float4 c = *(const float4*)(P + (size_t)2 * NN * 64 + (size_t)i4 * 4);
        float4 d = *(const float4*)(P + (size_t)3 * NN * 64 + (size_t)i4 * 4);
        float4 v = make_float4(a.x + b.x + c.x + d.x, a.y + b.y + c.y + d.y,
                               a.z + b.z + c.z + d.z, a.w + b.w + c.w + d.w);
        *(float4*)(agg + (size_t)i4 * 4) = v;
        float x0 = fmaxf(v.x, 0.f), x1 = fmaxf(v.y, 0.f);
        float x2 = fmaxf(v.z, 0.f), x3 = fmaxf(v.w, 0.f);
        s1v[0] += x0; s2v[0] += x0 * x0;
        s1v[1] += x1; s2v[1] += x1 * x1;
        s1v[2] += x2; s2v[2] += x2 * x2;
        s1v[3] += x3; s2v[3] += x3 * x3;
        atomicAdd(&pl[g * 64 + cl + 0], x0);
        atomicAdd(&pl[g * 64 + cl + 1], x1);
        atomicAdd(&pl[g * 64 + cl + 2], x2);
        atomicAdd(&pl[g * 64 + cl + 3], x3);
    }
    int grp = tx >> 4;
#pragma unroll
    for (int c = 0; c < 4; c++) {
        r1[grp * 64 + col0 + c] = s1v[c];
        r2[grp * 64 + col0 + c] = s2v[c];
    }
    __syncthreads();
    if (tx < 64) {
        float a = 0.f, b = 0.f;
#pragma unroll
        for (int g = 0; g < 16; g++) { a += r1[g * 64 + tx]; b += r2[g * 64 + tx]; }
        atomicAdd(&sums[tx], a);
        atomicAdd(&sumsq[tx], b);
    }
    __syncthreads();
    for (int t = tx; t < NG * 64; t += 256) {
        float v = pl[t];
        if (v != 0.f) atomicAdd(&Xg[t], v);
    }
}

// ---------------------------------------------------------------------------
// Classifier on pooled features via the pooled-BN identity:
//   pooled(h_new)[g,k] = gamma_k*r_k*(Xg[g,k] - c_g*mu_k) + c_g*beta_k
//                        + sc*pooled(h_old)[g,k]
// ---------------------------------------------------------------------------
__device__ __forceinline__ void classifier_body(int tx,
        const float* __restrict__ sums, const float* __restrict__ sumsq,
        const float* __restrict__ Xg, const int* __restrict__ gcnt,
        float* __restrict__ Pold,
        const float* __restrict__ gamma, const float* __restrict__ beta,
        const float* __restrict__ cW1, const float* __restrict__ cb1,
        const float* __restrict__ cg1, const float* __restrict__ cbt1,
        const float* __restrict__ cW2, const float* __restrict__ cb2,
        float* __restrict__ logits, int sc) {
    __shared__ float Pn[NG * 64];
    __shared__ float H1s[NG * 32];
    __shared__ float cmu[32], crs[32];
    for (int t = tx; t < NG * 64; t += 256) {
        int g = t >> 6, k = t & 63;
        float mean = sums[k] * (1.f / NN);
        float var  = sumsq[k] * (1.f / NN) - mean * mean;
        float r = rsqrtf(var + 1e-5f);
        float cg = (float)gcnt[g];
        float v = gamma[k] * r * (Xg[t] - cg * mean) + cg * beta[k];
        if (sc) v += Pold[t];
        Pn[t] = v;
        Pold[t] = v;
    }
    __syncthreads();
    for (int t = tx; t < NG * 32; t += 256) {
        int g = t >> 5, c = t & 31;
        float acc = cb1[c];
#pragma unroll 16
        for (int j = 0; j < 64; j++) acc = fmaf(Pn[g * 64 + j], cW1[j * 32 + c], acc);
        H1s[t] = acc;
    }
    __syncthreads();
    if (tx < 32) {
        float mu = 0.f;
#pragma unroll
        for (int g2 = 0; g2 < NG; g2++) mu += H1s[g2 * 32 + tx];
        mu *= (1.f / NG);
        float v = 0.f;
#pragma unroll
        for (int g2 = 0; g2 < NG; g2++) {
            float d = H1s[g2 * 32 + tx] - mu;
            v += d * d;
        }
        v *= (1.f / NG);
        cmu[tx] = mu;
        crs[tx] = rsqrtf(v + 1e-5f);
    }
    __syncthreads();
    for (int t = tx; t < NG * 32; t += 256) {
        int c = t & 31;
        H1s[t] = fmaxf(cg1[c] * (H1s[t] - cmu[c]) * crs[c] + cbt1[c], 0.f);
    }
    __syncthreads();
    if (tx < NG * NC) {
        int g = tx / NC, cls = tx % NC;
        float a2 = cb2[cls];
#pragma unroll
        for (int j = 0; j < 32; j++) a2 = fmaf(H1s[g * 32 + j], cW2[j * NC + cls], a2);
        logits[tx] += a2;
    }
}

// ---------------------------------------------------------------------------
// K4: BN apply + shortcut -> h_new; block 0 additionally runs the classifier.
// ---------------------------------------------------------------------------
__global__ __launch_bounds__(256) void bn_apply_k(const float* __restrict__ agg,
        const float* __restrict__ h_old, const float* __restrict__ sums,
        const float* __restrict__ sumsq, const float* __restrict__ gamma,
        const float* __restrict__ beta, float* __restrict__ h_new, int shortcut,
        const float* __restrict__ Xg, const int* __restrict__ gcnt,
        float* __restrict__ Pold,
        const float* __restrict__ cW1, const float* __restrict__ cb1,
        const float* __restrict__ cg1, const float* __restrict__ cbt1,
        const float* __restrict__ cW2, const float* __restrict__ cb2,
        float* __restrict__ logits) {
    int tx = threadIdx.x;
    int k = tx & 63;
    float mean = sums[k] * (1.f / NN);
    float var  = sumsq[k] * (1.f / NN) - mean * mean;
    float rstd = rsqrtf(var + 1e-5f);
    float g = gamma[k], b = beta[k];
    int idx0 = blockIdx.x * 256 + tx;
    int stride = gridDim.x * 256;
    for (int idx = idx0; idx < NN * 64; idx += stride) {
        float x = fmaxf(agg[idx], 0.f);
        float y = g * (x - mean) * rstd + b;
        if (shortcut) y += h_old[idx];
        h_new[idx] = y;
    }
    if (blockIdx.x == 0)
        classifier_body(tx, sums, sumsq, Xg, gcnt, Pold, gamma, beta,
                        cW1, cb1, cg1, cbt1, cW2, cb2, logits, shortcut);
}

// Layer 2: h_new is never consumed -> classifier only (1 block).
__global__ __launch_bounds__(256) void classifier_only_k(
        const float* __restrict__ sums, const float* __restrict__ sumsq,
        const float* __restrict__ Xg, const int* __restrict__ gcnt,
        float* __restrict__ Pold,
        const float* __restrict__ gamma, const float* __restrict__ beta,
        const float* __restrict__ cW1, const float* __restrict__ cb1,
        const float* __restrict__ cg1, const float* __restrict__ cbt1,
        const float* __restrict__ cW2, const float* __restrict__ cb2,
        float* __restrict__ logits) {
    classifier_body(threadIdx.x, sums, sumsq, Xg, gcnt, Pold, gamma, beta,
                    cW1, cb1, cg1, cbt1, cW2, cb2, logits, 1);
}

// ---------------------------------------------------------------------------
extern "C" void kernel_launch(void* const* d_in, const int* in_sizes, int n_in,
                              void* d_out, int out_size, void* d_ws, size_t ws_size,
                              hipStream_t stream) {
    const float* feature = (const float*)d_in[0];
    const float* cemb    = (const float*)d_in[1];
    const int*   src     = (const int*)d_in[2];
    const int*   dst     = (const int*)d_in[3];
    const int*   gids    = (const int*)d_in[4];
    const float* W[3]    = {(const float*)d_in[5], (const float*)d_in[6], (const float*)d_in[7]};
    const float* gam[3]  = {(const float*)d_in[8], (const float*)d_in[10], (const float*)d_in[12]};
    const float* bet[3]  = {(const float*)d_in[9], (const float*)d_in[11], (const float*)d_in[13]};
    const float* cW1  = (const float*)d_in[14];
    const float* cb1  = (const float*)d_in[15];
    const float* cg1  = (const float*)d_in[16];
    const float* cbt1 = (const float*)d_in[17];
    const float* cW2  = (const float*)d_in[18];
    const float* cb2  = (const float*)d_in[19];
    float* out = (float*)d_out;

    // workspace layout (4-byte units)
    float* ws      = (float*)d_ws;
    float* E       = ws;                           // NN*512  = 12,800,000
    float* Pparts  = E + (size_t)NN * 512;         // 4*NN*64 = 6,400,000
    float* dnorm_d = Pparts + (size_t)4 * NN * 64; // NE*8    = 3,200,000
    float* bufX    = dnorm_d + (size_t)NE * 8;     // NN*64
    float* bufY    = bufX + (size_t)NN * 64;       // NN*64
    float* sums    = bufY + (size_t)NN * 64;       // 64   } contiguous 1152
    float* sumsq   = sums + 64;                    // 64   } zeroed by edge_E
    float* Xg      = sumsq + 64;                   // 1024 } block 0
    float* Pold    = Xg + 1024;                    // 1024 (persists across layers)
    int*   cnt     = (int*)(Pold + 1024);          // NN
    int*   gcnt    = cnt + NN;                     // 16 (written by scan_mid, no atomics)
    int*   cur     = gcnt + 16;                    // NN
    int*   dstoff  = cur + NN;                     // NN+1 (pad +8)
    int*   bsum    = dstoff + NN + 8;              // 128
    int*   boff    = bsum + 128;                   // 128
    int*   src_d   = boff + 128;                   // NE

    hipMemsetAsync(d_out, 0, (size_t)NG * NC * sizeof(float), stream);
    hipMemsetAsync(cnt, 0, NN * sizeof(int), stream);

    hist_k<<<(NE + 255) / 256, 256, 0, stream>>>(dst, cnt);
    scan_part_k<<<SCAN_NB, 256, 0, stream>>>(cnt, bsum);
    scan_mid_k<<<1, 128, 0, stream>>>(bsum, boff, dstoff, gids, gcnt);
    scan_final_k<<<SCAN_NB, 256, 0, stream>>>(cnt, boff, dstoff, cur);
    scatter_k<<<(NE + 255) / 256, 256, 0, stream>>>(src, dst, cemb, cur, src_d, dnorm_d);

    const float* h_old = feature;
    float* bufs[2] = {bufX, bufY};
    for (int l = 0; l < 3; l++) {
        float* agg = bufs[l & 1];
        edge_E_k<<<NWE / 4, 256, 0, stream>>>(src_d, dstoff, dnorm_d, h_old, E, sums);
        finish_gemm_part_k<<<dim3((NN + 63) / 64, 4), 256, 0, stream>>>(E, W[l], Pparts);
        combine_stats_k<<<512, 256, 0, stream>>>(Pparts, gids, agg, sums, sumsq, Xg);
        if (l < 2) {
            bn_apply_k<<<256, 256, 0, stream>>>(agg, h_old, sums, sumsq, gam[l], bet[l],
                                                agg, l > 0, Xg, gcnt, Pold,
                                                cW1, cb1, cg1, cbt1, cW2, cb2, out);
        } else {
            classifier_only_k<<<1, 256, 0, stream>>>(sums, sumsq, Xg, gcnt, Pold,
                                                     gam[l], bet[l],
                                                     cW1, cb1, cg1, cbt1, cW2, cb2, out);
        }
        h_old = agg;
    }
}

// Round 10
// 504.211 us; speedup vs baseline: 1.3274x; 1.0589x over previous
//
#include <hip/hip_runtime.h>
#include <math.h>

#define NN 25000
#define NE 400000
#define HD 64
#define EMBD 8
#define NG 16
#define NC 10
#define SCAN_NB 98   // ceil(NN/256)

// ---------------------------------------------------------------------------
// Sort phase: dst-CSR (edge structure is layer-invariant).
// ---------------------------------------------------------------------------
__global__ __launch_bounds__(256) void hist_k(const int* __restrict__ dst, int* cnt) {
    int e = blockIdx.x * 256 + threadIdx.x;
    if (e < NE) atomicAdd(&cnt[dst[e]], 1);
}

__global__ __launch_bounds__(256) void scan_part_k(const int* __restrict__ cnt, int* bsum) {
    __shared__ int sh[256];
    int tx = threadIdx.x;
    int i = blockIdx.x * 256 + tx;
    sh[tx] = (i < NN) ? cnt[i] : 0;
    __syncthreads();
    for (int off = 128; off > 0; off >>= 1) {
        if (tx < off) sh[tx] += sh[tx + off];
        __syncthreads();
    }
    if (tx == 0) bsum[blockIdx.x] = sh[0];
}

// single small block: scan of block sums; ALSO computes gcnt[g] by binary
// search over the (sorted) graph_ids — no atomics (sorted ids caused 175us
// same-bin atomic serialization in R8).
__global__ __launch_bounds__(128) void scan_mid_k(const int* __restrict__ bsum,
        int* boff, int* dstoff, const int* __restrict__ gids, int* gcnt) {
    __shared__ int sh[128];
    int tx = threadIdx.x;
    int v = (tx < SCAN_NB) ? bsum[tx] : 0;
    sh[tx] = v;
    __syncthreads();
    for (int off = 1; off < 128; off <<= 1) {
        int t = (tx >= off) ? sh[tx - off] : 0;
        __syncthreads();
        sh[tx] += t;
        __syncthreads();
    }
    if (tx < SCAN_NB) boff[tx] = sh[tx] - v;
    if (tx == 0) dstoff[NN] = NE;
    if (tx < NG) {
        int lo = 0, hi = NN;
        while (lo < hi) { int m = (lo + hi) >> 1; if (gids[m] < tx) lo = m + 1; else hi = m; }
        int a = lo;
        lo = 0; hi = NN;
        while (lo < hi) { int m = (lo + hi) >> 1; if (gids[m] < tx + 1) lo = m + 1; else hi = m; }
        gcnt[tx] = lo - a;
    }
}

__global__ __launch_bounds__(256) void scan_final_k(const int* __restrict__ cnt,
        const int* __restrict__ boff, int* dstoff, int* cur) {
    __shared__ int sh[256];
    int tx = threadIdx.x;
    int i = blockIdx.x * 256 + tx;
    int v = (i < NN) ? cnt[i] : 0;
    sh[tx] = v;
    __syncthreads();
    for (int off = 1; off < 256; off <<= 1) {
        int t = (tx >= off) ? sh[tx - off] : 0;
        __syncthreads();
        sh[tx] += t;
        __syncthreads();
    }
    int excl = boff[blockIdx.x] + sh[tx] - v;
    if (i < NN) { dstoff[i] = excl; cur[i] = excl; }
}

// scatter: place src at dst-sorted slot AND precompute normalized direction.
__global__ __launch_bounds__(256) void scatter_k(const int* __restrict__ src,
        const int* __restrict__ dst, const float* __restrict__ c,
        int* cur, int* __restrict__ src_d, float* __restrict__ dnorm_d) {
    int e = blockIdx.x * 256 + threadIdx.x;
    if (e >= NE) return;
    int s = src[e], t = dst[e];
    int pd = atomicAdd(&cur[t], 1);
    src_d[pd] = s;
    float4 sa = *(const float4*)(c + (size_t)s * 8);
    float4 sb = *(const float4*)(c + (size_t)s * 8 + 4);
    float4 na = *(const float4*)(c + (size_t)t * 8);
    float4 nb = *(const float4*)(c + (size_t)t * 8 + 4);
    float d0 = sa.x - na.x, d1 = sa.y - na.y, d2 = sa.z - na.z, d3 = sa.w - na.w;
    float d4 = sb.x - nb.x, d5 = sb.y - nb.y, d6 = sb.z - nb.z, d7 = sb.w - nb.w;
    float nn2 = d0*d0 + d1*d1 + d2*d2 + d3*d3 + d4*d4 + d5*d5 + d6*d6 + d7*d7;
    float inv = 1.f / fmaxf(sqrtf(nn2), 1e-12f);
    *(float4*)(dnorm_d + (size_t)pd * 8)     = make_float4(d0*inv, d1*inv, d2*inv, d3*inv);
    *(float4*)(dnorm_d + (size_t)pd * 8 + 4) = make_float4(d4*inv, d5*inv, d6*inv, d7*inv);
}

// ---------------------------------------------------------------------------
// K1: E[t, i*64+j] = sum_{e->t} dnorm[e,i] * h[src_e, j]
// Wave-cooperative src prefetch + masked 8-wide gather batches.
// ---------------------------------------------------------------------------
#define NWE 8192
__global__ __launch_bounds__(256) void edge_E_k(const int* __restrict__ src_d,
        const int* __restrict__ dstoff, const float* __restrict__ dnorm_d,
        const float* __restrict__ h, float* __restrict__ E,
        float* __restrict__ stats_zero) {
    if (blockIdx.x == 0) {
        for (int t = threadIdx.x; t < 64 + 64 + NG * 64; t += 256)
            stats_zero[t] = 0.f;
    }
    int gid  = blockIdx.x * 256 + threadIdx.x;
    int w    = gid >> 6;
    int lane = threadIdx.x & 63;
    long long t0 = (long long)w * NE / NWE;
    long long t1 = (long long)(w + 1) * NE / NWE;
    int lo = 0, hi = NN;
    while (lo < hi) { int mid = (lo + hi) >> 1; if (dstoff[mid] < t0) lo = mid + 1; else hi = mid; }
    int nlo = lo;
    lo = 0; hi = NN;
    while (lo < hi) { int mid = (lo + hi) >> 1; if (dstoff[mid] < t1) lo = mid + 1; else hi = mid; }
    int nhi = (w == NWE - 1) ? NN : lo;

    int wbase = -1000000;
    int sidx = 0;
    for (int n = nlo; n < nhi; n++) {
        float e0=0,e1=0,e2=0,e3=0,e4=0,e5=0,e6=0,e7=0;
        int p0 = dstoff[n], p1 = dstoff[n + 1];
        int p = p0;
        while (p < p1) {
            if (p - wbase > 56) {
                wbase = p;
                int ld = wbase + lane;
                if (ld > NE - 1) ld = NE - 1;
                sidx = src_d[ld];
            }
            int m = p1 - p; if (m > 8) m = 8;
            int sj[8]; float hj[8];
#pragma unroll
            for (int j = 0; j < 8; j++) sj[j] = __shfl(sidx, p + j - wbase);
#pragma unroll
            for (int j = 0; j < 8; j++)
                if (j < m) hj[j] = h[(size_t)sj[j] * 64 + lane];
#pragma unroll
            for (int j = 0; j < 8; j++)
                if (j < m) {
                    float4 dA = *(const float4*)(dnorm_d + (size_t)(p + j) * 8);
                    float4 dB = *(const float4*)(dnorm_d + (size_t)(p + j) * 8 + 4);
                    float hv = hj[j];
                    e0 = fmaf(dA.x, hv, e0); e1 = fmaf(dA.y, hv, e1);
                    e2 = fmaf(dA.z, hv, e2); e3 = fmaf(dA.w, hv, e3);
                    e4 = fmaf(dB.x, hv, e4); e5 = fmaf(dB.y, hv, e5);
                    e6 = fmaf(dB.z, hv, e6); e7 = fmaf(dB.w, hv, e7);
                }
            p += m;
        }
        float* ep = E + (size_t)n * 512 + lane;
        ep[0*64] = e0; ep[1*64] = e1; ep[2*64] = e2; ep[3*64] = e3;
        ep[4*64] = e4; ep[5*64] = e5; ep[6*64] = e6; ep[7*64] = e7;
    }
}

// ---------------------------------------------------------------------------
// K2: K-split finish GEMM (4 parts of K=128). 128-node x 64-col tile,
// 8x4 acc/thread: per q-step 3 ds_read_b128 feed 32 FMA (FMA-bound),
// half the LDS traffic per FLOP of the old 4x4 tile. 196x4 = 784 blocks,
// 50 KB LDS -> 3 blocks/CU (one clean residency round).
// ---------------------------------------------------------------------------
__global__ __launch_bounds__(256) void finish_gemm_part_k(const float* __restrict__ E,
        const float* __restrict__ W, float* __restrict__ P) {
    __shared__ float Et[64][132];   // [q][r], pad 132: MAC reads worst 4-way
    __shared__ float Wsh[64][64];   // [q][k]
    int n0 = blockIdx.x * 128;
    int part = blockIdx.y;
    int tx = threadIdx.x;
    int col0 = (tx & 15) * 4;
    int row0 = (tx >> 4) * 8;
    float acc[8][4] = {{0.f}};

    for (int c = 0; c < 2; c++) {
        __syncthreads();
        {   // stage Et transposed; float4 global reads over q
            int qq = tx & 15;       // 16 float4 = 64 q
            int r0 = tx >> 4;       // 0..15
            for (int rr = r0; rr < 128; rr += 16) {
                int n = n0 + rr;
                float4 v = (n < NN)
                    ? *(const float4*)(E + (size_t)n * 512 + part * 128 + c * 64 + qq * 4)
                    : make_float4(0.f, 0.f, 0.f, 0.f);
                Et[qq * 4 + 0][rr] = v.x;
                Et[qq * 4 + 1][rr] = v.y;
                Et[qq * 4 + 2][rr] = v.z;
                Et[qq * 4 + 3][rr] = v.w;
            }
        }
        {   // stage Wsh row-major; float4 global reads over k
            int kk = tx & 15;
            int q0 = tx >> 4;
            for (int q = q0; q < 64; q += 16)
                *(float4*)&Wsh[q][kk * 4] =
                    *(const float4*)(W + (size_t)(part * 2 + c) * 4096 + q * 64 + kk * 4);
        }
        __syncthreads();
#pragma unroll 4
        for (int q = 0; q < 64; q++) {
            float4 a0 = *(const float4*)&Et[q][row0];
            float4 a1 = *(const float4*)&Et[q][row0 + 4];
            float4 b  = *(const float4*)&Wsh[q][col0];
            float a8[8] = {a0.x, a0.y, a0.z, a0.w, a1.x, a1.y, a1.z, a1.w};
            float b4[4] = {b.x, b.y, b.z, b.w};
#pragma unroll
            for (int r = 0; r < 8; r++)
#pragma unroll
                for (int cc = 0; cc < 4; cc++)
                    acc[r][cc] = fmaf(a8[r], b4[cc], acc[r][cc]);
        }
    }
    float* Pp = P + (size_t)part * NN * 64;
#pragma unroll
    for (int r = 0; r < 8; r++) {
        int n = n0 + row0 + r;
        if (n < NN)
            *(float4*)(Pp + (size_t)n * 64 + col0) =
                make_float4(acc[r][0], acc[r][1], acc[r][2], acc[r][3]);
    }
}

// ---------------------------------------------------------------------------
// K3: combine 4 partials -> agg; fused relu BN-stats + per-graph sums Xg.
// ---------------------------------------------------------------------------
__global__ __launch_bounds__(256) void combine_stats_k(const float* __restrict__ P,
        const int* __restrict__ gids, float* __restrict__ agg,
        float* sums, float* sumsq, float* Xg) {
    __shared__ float pl[NG * 64];
    __shared__ float r1[16 * 64], r2[16 * 64];
    int tx = threadIdx.x;
    for (int t = tx; t < NG * 64; t += 256) pl[t] = 0.f;
    __syncthreads();
    int idx0 = blockIdx.x * 256 + tx;
    int stride = gridDim.x * 256;
    const int n4 = NN * 16;
    int col0 = (tx & 15) * 4;
    float s1v[4] = {0.f}, s2v[4] = {0.f};
    for (int i4 = idx0; i4 < n4; i4 += stride) {
        int n = i4 >> 4;
        int g = gids[n];
        int cl = (i4 & 15) * 4;
        float4 a = *(const float4*)(P + (size_t)i4 * 4);
        float4 b = *(const float4*)(P + (size_t)NN * 64 + (size_t)i4 * 4);
        float4 c = *(const float4*)(P + (size_t)2 * NN * 64 + (size_t)i4 * 4);
        float4 d = *(const float4*)(P + (size_t)3 * NN * 64 + (size_t)i4 * 4);
        float4 v = make_float4(a.x + b.x + c.x + d.x, a.y + b.y + c.y + d.y,
                               a.z + b.z + c.z + d.z, a.w + b.w + c.w + d.w);
        *(float4*)(agg + (size_t)i4 * 4) = v;
        float x0 = fmaxf(v.x, 0.f), x1 = fmaxf(v.y, 0.f);
        float x2 = fmaxf(v.z, 0.f), x3 = fmaxf(v.w, 0.f);
        s1v[0] += x0; s2v[0] += x0 * x0;
        s1v[1] += x1; s2v[1] += x1 * x1;
        s1v[2] += x2; s2v[2] += x2 * x2;
        s1v[3] += x3; s2v[3] += x3 * x3;
        atomicAdd(&pl[g * 64 + cl + 0], x0);
        atomicAdd(&pl[g * 64 + cl + 1], x1);
        atomicAdd(&pl[g * 64 + cl + 2], x2);
        atomicAdd(&pl[g * 64 + cl + 3], x3);
    }
    int grp = tx >> 4;
#pragma unroll
    for (int c = 0; c < 4; c++) {
        r1[grp * 64 + col0 + c] = s1v[c];
        r2[grp * 64 + col0 + c] = s2v[c];
    }
    __syncthreads();
    if (tx < 64) {
        float a = 0.f, b = 0.f;
#pragma unroll
        for (int g = 0; g < 16; g++) { a += r1[g * 64 + tx]; b += r2[g * 64 + tx]; }
        atomicAdd(&sums[tx], a);
        atomicAdd(&sumsq[tx], b);
    }
    __syncthreads();
    for (int t = tx; t < NG * 64; t += 256) {
        float v = pl[t];
        if (v != 0.f) atomicAdd(&Xg[t], v);
    }
}

// ---------------------------------------------------------------------------
// Classifier via pooled-BN identity:
//   pooled(h_new)[g,k] = gamma_k*r_k*(Xg[g,k] - c_g*mu_k) + c_g*beta_k
//                        + sc*pooled(h_old)[g,k]
// ---------------------------------------------------------------------------
__device__ __forceinline__ void classifier_body(int tx,
        const float* __restrict__ sums, const float* __restrict__ sumsq,
        const float* __restrict__ Xg, const int* __restrict__ gcnt,
        float* __restrict__ Pold,
        const float* __restrict__ gamma, const float* __restrict__ beta,
        const float* __restrict__ cW1, const float* __restrict__ cb1,
        const float* __restrict__ cg1, const float* __restrict__ cbt1,
        const float* __restrict__ cW2, const float* __restrict__ cb2,
        float* __restrict__ logits, int sc) {
    __shared__ float Pn[NG * 64];
    __shared__ float H1s[NG * 32];
    __shared__ float cmu[32], crs[32];
    for (int t = tx; t < NG * 64; t += 256) {
        int g = t >> 6, k = t & 63;
        float mean = sums[k] * (1.f / NN);
        float var  = sumsq[k] * (1.f / NN) - mean * mean;
        float r = rsqrtf(var + 1e-5f);
        float cg = (float)gcnt[g];
        float v = gamma[k] * r * (Xg[t] - cg * mean) + cg * beta[k];
        if (sc) v += Pold[t];
        Pn[t] = v;
        Pold[t] = v;
    }
    __syncthreads();
    for (int t = tx; t < NG * 32; t += 256) {
        int g = t >> 5, c = t & 31;
        float acc = cb1[c];
#pragma unroll 16
        for (int j = 0; j < 64; j++) acc = fmaf(Pn[g * 64 + j], cW1[j * 32 + c], acc);
        H1s[t] = acc;
    }
    __syncthreads();
    if (tx < 32) {
        float mu = 0.f;
#pragma unroll
        for (int g2 = 0; g2 < NG; g2++) mu += H1s[g2 * 32 + tx];
        mu *= (1.f / NG);
        float v = 0.f;
#pragma unroll
        for (int g2 = 0; g2 < NG; g2++) {
            float d = H1s[g2 * 32 + tx] - mu;
            v += d * d;
        }
        v *= (1.f / NG);
        cmu[tx] = mu;
        crs[tx] = rsqrtf(v + 1e-5f);
    }
    __syncthreads();
    for (int t = tx; t < NG * 32; t += 256) {
        int c = t & 31;
        H1s[t] = fmaxf(cg1[c] * (H1s[t] - cmu[c]) * crs[c] + cbt1[c], 0.f);
    }
    __syncthreads();
    if (tx < NG * NC) {
        int g = tx / NC, cls = tx % NC;
        float a2 = cb2[cls];
#pragma unroll
        for (int j = 0; j < 32; j++) a2 = fmaf(H1s[g * 32 + j], cW2[j * NC + cls], a2);
        logits[tx] += a2;
    }
}

// ---------------------------------------------------------------------------
// K4: BN apply + shortcut -> h_new; block 0 also runs the classifier.
// ---------------------------------------------------------------------------
__global__ __launch_bounds__(256) void bn_apply_k(const float* __restrict__ agg,
        const float* __restrict__ h_old, const float* __restrict__ sums,
        const float* __restrict__ sumsq, const float* __restrict__ gamma,
        const float* __restrict__ beta, float* __restrict__ h_new, int shortcut,
        const float* __restrict__ Xg, const int* __restrict__ gcnt,
        float* __restrict__ Pold,
        const float* __restrict__ cW1, const float* __restrict__ cb1,
        const float* __restrict__ cg1, const float* __restrict__ cbt1,
        const float* __restrict__ cW2, const float* __restrict__ cb2,
        float* __restrict__ logits) {
    int tx = threadIdx.x;
    int k = tx & 63;
    float mean = sums[k] * (1.f / NN);
    float var  = sumsq[k] * (1.f / NN) - mean * mean;
    float rstd = rsqrtf(var + 1e-5f);
    float g = gamma[k], b = beta[k];
    int idx0 = blockIdx.x * 256 + tx;
    int stride = gridDim.x * 256;
    for (int idx = idx0; idx < NN * 64; idx += stride) {
        float x = fmaxf(agg[idx], 0.f);
        float y = g * (x - mean) * rstd + b;
        if (shortcut) y += h_old[idx];
        h_new[idx] = y;
    }
    if (blockIdx.x == 0)
        classifier_body(tx, sums, sumsq, Xg, gcnt, Pold, gamma, beta,
                        cW1, cb1, cg1, cbt1, cW2, cb2, logits, shortcut);
}

// Layer 2: h_new is never consumed -> classifier only (1 block).
__global__ __launch_bounds__(256) void classifier_only_k(
        const float* __restrict__ sums, const float* __restrict__ sumsq,
        const float* __restrict__ Xg, const int* __restrict__ gcnt,
        float* __restrict__ Pold,
        const float* __restrict__ gamma, const float* __restrict__ beta,
        const float* __restrict__ cW1, const float* __restrict__ cb1,
        const float* __restrict__ cg1, const float* __restrict__ cbt1,
        const float* __restrict__ cW2, const float* __restrict__ cb2,
        float* __restrict__ logits) {
    classifier_body(threadIdx.x, sums, sumsq, Xg, gcnt, Pold, gamma, beta,
                    cW1, cb1, cg1, cbt1, cW2, cb2, logits, 1);
}

// ---------------------------------------------------------------------------
extern "C" void kernel_launch(void* const* d_in, const int* in_sizes, int n_in,
                              void* d_out, int out_size, void* d_ws, size_t ws_size,
                              hipStream_t stream) {
    const float* feature = (const float*)d_in[0];
    const float* cemb    = (const float*)d_in[1];
    const int*   src     = (const int*)d_in[2];
    const int*   dst     = (const int*)d_in[3];
    const int*   gids    = (const int*)d_in[4];
    const float* W[3]    = {(const float*)d_in[5], (const float*)d_in[6], (const float*)d_in[7]};
    const float* gam[3]  = {(const float*)d_in[8], (const float*)d_in[10], (const float*)d_in[12]};
    const float* bet[3]  = {(const float*)d_in[9], (const float*)d_in[11], (const float*)d_in[13]};
    const float* cW1  = (const float*)d_in[14];
    const float* cb1  = (const float*)d_in[15];
    const float* cg1  = (const float*)d_in[16];
    const float* cbt1 = (const float*)d_in[17];
    const float* cW2  = (const float*)d_in[18];
    const float* cb2  = (const float*)d_in[19];
    float* out = (float*)d_out;

    // workspace layout (4-byte units)
    float* ws      = (float*)d_ws;
    float* E       = ws;                           // NN*512  = 12,800,000
    float* Pparts  = E + (size_t)NN * 512;         // 4*NN*64 = 6,400,000
    float* dnorm_d = Pparts + (size_t)4 * NN * 64; // NE*8    = 3,200,000
    float* bufX    = dnorm_d + (size_t)NE * 8;     // NN*64
    float* bufY    = bufX + (size_t)NN * 64;       // NN*64
    float* sums    = bufY + (size_t)NN * 64;       // 64   } contiguous 1152
    float* sumsq   = sums + 64;                    // 64   } zeroed by edge_E
    float* Xg      = sumsq + 64;                   // 1024 } block 0
    float* Pold    = Xg + 1024;                    // 1024 (persists across layers)
    int*   cnt     = (int*)(Pold + 1024);          // NN
    int*   gcnt    = cnt + NN;                     // 16 (scan_mid, no atomics)
    int*   cur     = gcnt + 16;                    // NN
    int*   dstoff  = cur + NN;                     // NN+1 (pad +8)
    int*   bsum    = dstoff + NN + 8;              // 128
    int*   boff    = bsum + 128;                   // 128
    int*   src_d   = boff + 128;                   // NE

    hipMemsetAsync(d_out, 0, (size_t)NG * NC * sizeof(float), stream);
    hipMemsetAsync(cnt, 0, NN * sizeof(int), stream);

    hist_k<<<(NE + 255) / 256, 256, 0, stream>>>(dst, cnt);
    scan_part_k<<<SCAN_NB, 256, 0, stream>>>(cnt, bsum);
    scan_mid_k<<<1, 128, 0, stream>>>(bsum, boff, dstoff, gids, gcnt);
    scan_final_k<<<SCAN_NB, 256, 0, stream>>>(cnt, boff, dstoff, cur);
    scatter_k<<<(NE + 255) / 256, 256, 0, stream>>>(src, dst, cemb, cur, src_d, dnorm_d);

    const float* h_old = feature;
    float* bufs[2] = {bufX, bufY};
    for (int l = 0; l < 3; l++) {
        float* agg = bufs[l & 1];
        edge_E_k<<<NWE / 4, 256, 0, stream>>>(src_d, dstoff, dnorm_d, h_old, E, sums);
        finish_gemm_part_k<<<dim3((NN + 127) / 128, 4), 256, 0, stream>>>(E, W[l], Pparts);
        combine_stats_k<<<512, 256, 0, stream>>>(Pparts, gids, agg, sums, sumsq, Xg);
        if (l < 2) {
            bn_apply_k<<<256, 256, 0, stream>>>(agg, h_old, sums, sumsq, gam[l], bet[l],
                                                agg, l > 0, Xg, gcnt, Pold,
                                                cW1, cb1, cg1, cbt1, cW2, cb2, out);
        } else {
            classifier_only_k<<<1, 256, 0, stream>>>(sums, sumsq, Xg, gcnt, Pold,
                                                     gam[l], bet[l],
                                                     cW1, cb1, cg1, cbt1, cW2, cb2, out);
        }
        h_old = agg;
    }
}

// Round 11
// 503.579 us; speedup vs baseline: 1.3291x; 1.0013x over previous
//
#include <hip/hip_runtime.h>
#include <hip/hip_fp16.h>
#include <math.h>

#define NN 25000
#define NE 400000
#define HD 64
#define EMBD 8
#define NG 16
#define NC 10
#define SCAN_NB 98   // ceil(NN/256)

// ---------------------------------------------------------------------------
// Sort phase: dst-CSR (edge structure is layer-invariant).
// ---------------------------------------------------------------------------
__global__ __launch_bounds__(256) void hist_k(const int* __restrict__ dst, int* cnt) {
    int e = blockIdx.x * 256 + threadIdx.x;
    if (e < NE) atomicAdd(&cnt[dst[e]], 1);
}

__global__ __launch_bounds__(256) void scan_part_k(const int* __restrict__ cnt, int* bsum) {
    __shared__ int sh[256];
    int tx = threadIdx.x;
    int i = blockIdx.x * 256 + tx;
    sh[tx] = (i < NN) ? cnt[i] : 0;
    __syncthreads();
    for (int off = 128; off > 0; off >>= 1) {
        if (tx < off) sh[tx] += sh[tx + off];
        __syncthreads();
    }
    if (tx == 0) bsum[blockIdx.x] = sh[0];
}

// scan of block sums + gcnt[g] via binary search on sorted gids (no atomics:
// sorted ids caused 175us same-bin atomic serialization in R8).
__global__ __launch_bounds__(128) void scan_mid_k(const int* __restrict__ bsum,
        int* boff, int* dstoff, const int* __restrict__ gids, int* gcnt) {
    __shared__ int sh[128];
    int tx = threadIdx.x;
    int v = (tx < SCAN_NB) ? bsum[tx] : 0;
    sh[tx] = v;
    __syncthreads();
    for (int off = 1; off < 128; off <<= 1) {
        int t = (tx >= off) ? sh[tx - off] : 0;
        __syncthreads();
        sh[tx] += t;
        __syncthreads();
    }
    if (tx < SCAN_NB) boff[tx] = sh[tx] - v;
    if (tx == 0) dstoff[NN] = NE;
    if (tx < NG) {
        int lo = 0, hi = NN;
        while (lo < hi) { int m = (lo + hi) >> 1; if (gids[m] < tx) lo = m + 1; else hi = m; }
        int a = lo;
        lo = 0; hi = NN;
        while (lo < hi) { int m = (lo + hi) >> 1; if (gids[m] < tx + 1) lo = m + 1; else hi = m; }
        gcnt[tx] = lo - a;
    }
}

__global__ __launch_bounds__(256) void scan_final_k(const int* __restrict__ cnt,
        const int* __restrict__ boff, int* dstoff, int* cur) {
    __shared__ int sh[256];
    int tx = threadIdx.x;
    int i = blockIdx.x * 256 + tx;
    int v = (i < NN) ? cnt[i] : 0;
    sh[tx] = v;
    __syncthreads();
    for (int off = 1; off < 256; off <<= 1) {
        int t = (tx >= off) ? sh[tx - off] : 0;
        __syncthreads();
        sh[tx] += t;
        __syncthreads();
    }
    int excl = boff[blockIdx.x] + sh[tx] - v;
    if (i < NN) { dstoff[i] = excl; cur[i] = excl; }
}

// scatter: place src at dst-sorted slot AND precompute normalized direction.
__global__ __launch_bounds__(256) void scatter_k(const int* __restrict__ src,
        const int* __restrict__ dst, const float* __restrict__ c,
        int* cur, int* __restrict__ src_d, float* __restrict__ dnorm_d) {
    int e = blockIdx.x * 256 + threadIdx.x;
    if (e >= NE) return;
    int s = src[e], t = dst[e];
    int pd = atomicAdd(&cur[t], 1);
    src_d[pd] = s;
    float4 sa = *(const float4*)(c + (size_t)s * 8);
    float4 sb = *(const float4*)(c + (size_t)s * 8 + 4);
    float4 na = *(const float4*)(c + (size_t)t * 8);
    float4 nb = *(const float4*)(c + (size_t)t * 8 + 4);
    float d0 = sa.x - na.x, d1 = sa.y - na.y, d2 = sa.z - na.z, d3 = sa.w - na.w;
    float d4 = sb.x - nb.x, d5 = sb.y - nb.y, d6 = sb.z - nb.z, d7 = sb.w - nb.w;
    float nn2 = d0*d0 + d1*d1 + d2*d2 + d3*d3 + d4*d4 + d5*d5 + d6*d6 + d7*d7;
    float inv = 1.f / fmaxf(sqrtf(nn2), 1e-12f);
    *(float4*)(dnorm_d + (size_t)pd * 8)     = make_float4(d0*inv, d1*inv, d2*inv, d3*inv);
    *(float4*)(dnorm_d + (size_t)pd * 8 + 4) = make_float4(d4*inv, d5*inv, d6*inv, d7*inv);
}

// one-time fp16 shadow of the layer-0 features (gather bandwidth halver)
__global__ __launch_bounds__(256) void cast_h16_k(const float* __restrict__ h,
        __half* __restrict__ h16) {
    int i4 = blockIdx.x * 256 + threadIdx.x;
    if (i4 >= NN * 16) return;
    float4 v = *(const float4*)(h + (size_t)i4 * 4);
    __half2 lo = __floats2half2_rn(v.x, v.y);
    __half2 hi = __floats2half2_rn(v.z, v.w);
    *(__half2*)(h16 + (size_t)i4 * 4)     = lo;
    *(__half2*)(h16 + (size_t)i4 * 4 + 2) = hi;
}

// ---------------------------------------------------------------------------
// K1: E[t, i*64+j] = sum_{e->t} dnorm[e,i] * h[src_e, j]
// fp16 h gather: 128 B/edge = 2 cache lines (was 4) — the gather is
// L1-miss-queue limited, so lines/gather is the cost metric.
// Wave-cooperative src prefetch + masked 8-wide gather batches.
// ---------------------------------------------------------------------------
#define NWE 8192
__global__ __launch_bounds__(256) void edge_E_k(const int* __restrict__ src_d,
        const int* __restrict__ dstoff, const float* __restrict__ dnorm_d,
        const __half* __restrict__ h16, float* __restrict__ E,
        float* __restrict__ stats_zero) {
    if (blockIdx.x == 0) {
        for (int t = threadIdx.x; t < 64 + 64 + NG * 64; t += 256)
            stats_zero[t] = 0.f;
    }
    int gid  = blockIdx.x * 256 + threadIdx.x;
    int w    = gid >> 6;
    int lane = threadIdx.x & 63;
    long long t0 = (long long)w * NE / NWE;
    long long t1 = (long long)(w + 1) * NE / NWE;
    int lo = 0, hi = NN;
    while (lo < hi) { int mid = (lo + hi) >> 1; if (dstoff[mid] < t0) lo = mid + 1; else hi = mid; }
    int nlo = lo;
    lo = 0; hi = NN;
    while (lo < hi) { int mid = (lo + hi) >> 1; if (dstoff[mid] < t1) lo = mid + 1; else hi = mid; }
    int nhi = (w == NWE - 1) ? NN : lo;

    int wbase = -1000000;
    int sidx = 0;
    for (int n = nlo; n < nhi; n++) {
        float e0=0,e1=0,e2=0,e3=0,e4=0,e5=0,e6=0,e7=0;
        int p0 = dstoff[n], p1 = dstoff[n + 1];
        int p = p0;
        while (p < p1) {
            if (p - wbase > 56) {
                wbase = p;
                int ld = wbase + lane;
                if (ld > NE - 1) ld = NE - 1;
                sidx = src_d[ld];
            }
            int m = p1 - p; if (m > 8) m = 8;
            int sj[8]; __half hj[8];
#pragma unroll
            for (int j = 0; j < 8; j++) sj[j] = __shfl(sidx, p + j - wbase);
#pragma unroll
            for (int j = 0; j < 8; j++)
                if (j < m) hj[j] = h16[(size_t)sj[j] * 64 + lane];
#pragma unroll
            for (int j = 0; j < 8; j++)
                if (j < m) {
                    float4 dA = *(const float4*)(dnorm_d + (size_t)(p + j) * 8);
                    float4 dB = *(const float4*)(dnorm_d + (size_t)(p + j) * 8 + 4);
                    float hv = __half2float(hj[j]);
                    e0 = fmaf(dA.x, hv, e0); e1 = fmaf(dA.y, hv, e1);
                    e2 = fmaf(dA.z, hv, e2); e3 = fmaf(dA.w, hv, e3);
                    e4 = fmaf(dB.x, hv, e4); e5 = fmaf(dB.y, hv, e5);
                    e6 = fmaf(dB.z, hv, e6); e7 = fmaf(dB.w, hv, e7);
                }
            p += m;
        }
        float* ep = E + (size_t)n * 512 + lane;
        ep[0*64] = e0; ep[1*64] = e1; ep[2*64] = e2; ep[3*64] = e3;
        ep[4*64] = e4; ep[5*64] = e5; ep[6*64] = e6; ep[7*64] = e7;
    }
}

// ---------------------------------------------------------------------------
// K2: K-split finish GEMM (4 parts of K=128). 128x64 tile, 8x4 acc/thread.
// ---------------------------------------------------------------------------
__global__ __launch_bounds__(256) void finish_gemm_part_k(const float* __restrict__ E,
        const float* __restrict__ W, float* __restrict__ P) {
    __shared__ float Et[64][132];
    __shared__ float Wsh[64][64];
    int n0 = blockIdx.x * 128;
    int part = blockIdx.y;
    int tx = threadIdx.x;
    int col0 = (tx & 15) * 4;
    int row0 = (tx >> 4) * 8;
    float acc[8][4] = {{0.f}};

    for (int c = 0; c < 2; c++) {
        __syncthreads();
        {
            int qq = tx & 15;
            int r0 = tx >> 4;
            for (int rr = r0; rr < 128; rr += 16) {
                int n = n0 + rr;
                float4 v = (n < NN)
                    ? *(const float4*)(E + (size_t)n * 512 + part * 128 + c * 64 + qq * 4)
                    : make_float4(0.f, 0.f, 0.f, 0.f);
                Et[qq * 4 + 0][rr] = v.x;
                Et[qq * 4 + 1][rr] = v.y;
                Et[qq * 4 + 2][rr] = v.z;
                Et[qq * 4 + 3][rr] = v.w;
            }
        }
        {
            int kk = tx & 15;
            int q0 = tx >> 4;
            for (int q = q0; q < 64; q += 16)
                *(float4*)&Wsh[q][kk * 4] =
                    *(const float4*)(W + (size_t)(part * 2 + c) * 4096 + q * 64 + kk * 4);
        }
        __syncthreads();
#pragma unroll 4
        for (int q = 0; q < 64; q++) {
            float4 a0 = *(const float4*)&Et[q][row0];
            float4 a1 = *(const float4*)&Et[q][row0 + 4];
            float4 b  = *(const float4*)&Wsh[q][col0];
            float a8[8] = {a0.x, a0.y, a0.z, a0.w, a1.x, a1.y, a1.z, a1.w};
            float b4[4] = {b.x, b.y, b.z, b.w};
#pragma unroll
            for (int r = 0; r < 8; r++)
#pragma unroll
                for (int cc = 0; cc < 4; cc++)
                    acc[r][cc] = fmaf(a8[r], b4[cc], acc[r][cc]);
        }
    }
    float* Pp = P + (size_t)part * NN * 64;
#pragma unroll
    for (int r = 0; r < 8; r++) {
        int n = n0 + row0 + r;
        if (n < NN)
            *(float4*)(Pp + (size_t)n * 64 + col0) =
                make_float4(acc[r][0], acc[r][1], acc[r][2], acc[r][3]);
    }
}

// ---------------------------------------------------------------------------
// K3: combine 4 partials -> agg; fused relu BN-stats + per-graph sums Xg.
// ---------------------------------------------------------------------------
__global__ __launch_bounds__(256) void combine_stats_k(const float* __restrict__ P,
        const int* __restrict__ gids, float* __restrict__ agg,
        float* sums, float* sumsq, float* Xg) {
    __shared__ float pl[NG * 64];
    __shared__ float r1[16 * 64], r2[16 * 64];
    int tx = threadIdx.x;
    for (int t = tx; t < NG * 64; t += 256) pl[t] = 0.f;
    __syncthreads();
    int idx0 = blockIdx.x * 256 + tx;
    int stride = gridDim.x * 256;
    const int n4 = NN * 16;
    int col0 = (tx & 15) * 4;
    float s1v[4] = {0.f}, s2v[4] = {0.f};
    for (int i4 = idx0; i4 < n4; i4 += stride) {
        int n = i4 >> 4;
        int g = gids[n];
        int cl = (i4 & 15) * 4;
        float4 a = *(const float4*)(P + (size_t)i4 * 4);
        float4 b = *(const float4*)(P + (size_t)NN * 64 + (size_t)i4 * 4);
        float4 c = *(const float4*)(P + (size_t)2 * NN * 64 + (size_t)i4 * 4);
        float4 d = *(const float4*)(P + (size_t)3 * NN * 64 + (size_t)i4 * 4);
        float4 v = make_float4(a.x + b.x + c.x + d.x, a.y + b.y + c.y + d.y,
                               a.z + b.z + c.z + d.z, a.w + b.w + c.w + d.w);
        *(float4*)(agg + (size_t)i4 * 4) = v;
        float x0 = fmaxf(v.x, 0.f), x1 = fmaxf(v.y, 0.f);
        float x2 = fmaxf(v.z, 0.f), x3 = fmaxf(v.w, 0.f);
        s1v[0] += x0; s2v[0] += x0 * x0;
        s1v[1] += x1; s2v[1] += x1 * x1;
        s1v[2] += x2; s2v[2] += x2 * x2;
        s1v[3] += x3; s2v[3] += x3 * x3;
        atomicAdd(&pl[g * 64 + cl + 0], x0);
        atomicAdd(&pl[g * 64 + cl + 1], x1);
        atomicAdd(&pl[g * 64 + cl + 2], x2);
        atomicAdd(&pl[g * 64 + cl + 3], x3);
    }
    int grp = tx >> 4;
#pragma unroll
    for (int c = 0; c < 4; c++) {
        r1[grp * 64 + col0 + c] = s1v[c];
        r2[grp * 64 + col0 + c] = s2v[c];
    }
    __syncthreads();
    if (tx < 64) {
        float a = 0.f, b = 0.f;
#pragma unroll
        for (int g = 0; g < 16; g++) { a += r1[g * 64 + tx]; b += r2[g * 64 + tx]; }
        atomicAdd(&sums[tx], a);
        atomicAdd(&sumsq[tx], b);
    }
    __syncthreads();
    for (int t = tx; t < NG * 64; t += 256) {
        float v = pl[t];
        if (v != 0.f) atomicAdd(&Xg[t], v);
    }
}

// ---------------------------------------------------------------------------
// Classifier via pooled-BN identity.
// ---------------------------------------------------------------------------
__device__ __forceinline__ void classifier_body(int tx,
        const float* __restrict__ sums, const float* __restrict__ sumsq,
        const float* __restrict__ Xg, const int* __restrict__ gcnt,
        float* __restrict__ Pold,
        const float* __restrict__ gamma, const float* __restrict__ beta,
        const float* __restrict__ cW1, const float* __restrict__ cb1,
        const float* __restrict__ cg1, const float* __restrict__ cbt1,
        const float* __restrict__ cW2, const float* __restrict__ cb2,
        float* __restrict__ logits, int sc) {
    __shared__ float Pn[NG * 64];
    __shared__ float H1s[NG * 32];
    __shared__ float cmu[32], crs[32];
    for (int t = tx; t < NG * 64; t += 256) {
        int g = t >> 6, k = t & 63;
        float mean = sums[k] * (1.f / NN);
        float var  = sumsq[k] * (1.f / NN) - mean * mean;
        float r = rsqrtf(var + 1e-5f);
        float cg = (float)gcnt[g];
        float v = gamma[k] * r * (Xg[t] - cg * mean) + cg * beta[k];
        if (sc) v += Pold[t];
        Pn[t] = v;
        Pold[t] = v;
    }
    __syncthreads();
    for (int t = tx; t < NG * 32; t += 256) {
        int g = t >> 5, c = t & 31;
        float acc = cb1[c];
#pragma unroll 16
        for (int j = 0; j < 64; j++) acc = fmaf(Pn[g * 64 + j], cW1[j * 32 + c], acc);
        H1s[t] = acc;
    }
    __syncthreads();
    if (tx < 32) {
        float mu = 0.f;
#pragma unroll
        for (int g2 = 0; g2 < NG; g2++) mu += H1s[g2 * 32 + tx];
        mu *= (1.f / NG);
        float v = 0.f;
#pragma unroll
        for (int g2 = 0; g2 < NG; g2++) {
            float d = H1s[g2 * 32 + tx] - mu;
            v += d * d;
        }
        v *= (1.f / NG);
        cmu[tx] = mu;
        crs[tx] = rsqrtf(v + 1e-5f);
    }
    __syncthreads();
    for (int t = tx; t < NG * 32; t += 256) {
        int c = t & 31;
        H1s[t] = fmaxf(cg1[c] * (H1s[t] - cmu[c]) * crs[c] + cbt1[c], 0.f);
    }
    __syncthreads();
    if (tx < NG * NC) {
        int g = tx / NC, cls = tx % NC;
        float a2 = cb2[cls];
#pragma unroll
        for (int j = 0; j < 32; j++) a2 = fmaf(H1s[g * 32 + j], cW2[j * NC + cls], a2);
        logits[tx] += a2;
    }
}

// ---------------------------------------------------------------------------
// K4: BN apply + shortcut -> h_new (fp32) AND fp16 shadow for next gather;
// block 0 also runs the classifier.
// ---------------------------------------------------------------------------
__global__ __launch_bounds__(256) void bn_apply_k(const float* __restrict__ agg,
        const float* __restrict__ h_old, const float* __restrict__ sums,
        const float* __restrict__ sumsq, const float* __restrict__ gamma,
        const float* __restrict__ beta, float* __restrict__ h_new,
        __half* __restrict__ h16_out, int shortcut,
        const float* __restrict__ Xg, const int* __restrict__ gcnt,
        float* __restrict__ Pold,
        const float* __restrict__ cW1, const float* __restrict__ cb1,
        const float* __restrict__ cg1, const float* __restrict__ cbt1,
        const float* __restrict__ cW2, const float* __restrict__ cb2,
        float* __restrict__ logits) {
    int tx = threadIdx.x;
    int k = tx & 63;
    float mean = sums[k] * (1.f / NN);
    float var  = sumsq[k] * (1.f / NN) - mean * mean;
    float rstd = rsqrtf(var + 1e-5f);
    float g = gamma[k], b = beta[k];
    int idx0 = blockIdx.x * 256 + tx;
    int stride = gridDim.x * 256;
    for (int idx = idx0; idx < NN * 64; idx += stride) {
        float x = fmaxf(agg[idx], 0.f);
        float y = g * (x - mean) * rstd + b;
        if (shortcut) y += h_old[idx];
        h_new[idx] = y;
        h16_out[idx] = __float2half_rn(y);
    }
    if (blockIdx.x == 0)
        classifier_body(tx, sums, sumsq, Xg, gcnt, Pold, gamma, beta,
                        cW1, cb1, cg1, cbt1, cW2, cb2, logits, shortcut);
}

// Layer 2: h_new never consumed -> classifier only (1 block).
__global__ __launch_bounds__(256) void classifier_only_k(
        const float* __restrict__ sums, const float* __restrict__ sumsq,
        const float* __restrict__ Xg, const int* __restrict__ gcnt,
        float* __restrict__ Pold,
        const float* __restrict__ gamma, const float* __restrict__ beta,
        const float* __restrict__ cW1, const float* __restrict__ cb1,
        const float* __restrict__ cg1, const float* __restrict__ cbt1,
        const float* __restrict__ cW2, const float* __restrict__ cb2,
        float* __restrict__ logits) {
    classifier_body(threadIdx.x, sums, sumsq, Xg, gcnt, Pold, gamma, beta,
                    cW1, cb1, cg1, cbt1, cW2, cb2, logits, 1);
}

// ---------------------------------------------------------------------------
extern "C" void kernel_launch(void* const* d_in, const int* in_sizes, int n_in,
                              void* d_out, int out_size, void* d_ws, size_t ws_size,
                              hipStream_t stream) {
    const float* feature = (const float*)d_in[0];
    const float* cemb    = (const float*)d_in[1];
    const int*   src     = (const int*)d_in[2];
    const int*   dst     = (const int*)d_in[3];
    const int*   gids    = (const int*)d_in[4];
    const float* W[3]    = {(const float*)d_in[5], (const float*)d_in[6], (const float*)d_in[7]};
    const float* gam[3]  = {(const float*)d_in[8], (const float*)d_in[10], (const float*)d_in[12]};
    const float* bet[3]  = {(const float*)d_in[9], (const float*)d_in[11], (const float*)d_in[13]};
    const float* cW1  = (const float*)d_in[14];
    const float* cb1  = (const float*)d_in[15];
    const float* cg1  = (const float*)d_in[16];
    const float* cbt1 = (const float*)d_in[17];
    const float* cW2  = (const float*)d_in[18];
    const float* cb2  = (const float*)d_in[19];
    float* out = (float*)d_out;

    // workspace layout (4-byte units)
    float* ws      = (float*)d_ws;
    float* E       = ws;                           // NN*512  = 12,800,000
    float* Pparts  = E + (size_t)NN * 512;         // 4*NN*64 = 6,400,000
    float* dnorm_d = Pparts + (size_t)4 * NN * 64; // NE*8    = 3,200,000
    float* bufX    = dnorm_d + (size_t)NE * 8;     // NN*64
    float* bufY    = bufX + (size_t)NN * 64;       // NN*64
    float* sums    = bufY + (size_t)NN * 64;       // 64   } contiguous 1152
    float* sumsq   = sums + 64;                    // 64   } zeroed by edge_E blk0
    float* Xg      = sumsq + 64;                   // 1024 }
    float* Pold    = Xg + 1024;                    // 1024 (persists across layers)
    int*   cnt     = (int*)(Pold + 1024);          // NN
    int*   gcnt    = cnt + NN;                     // 16
    int*   cur     = gcnt + 16;                    // NN
    int*   dstoff  = cur + NN;                     // NN+1 (pad +8)
    int*   bsum    = dstoff + NN + 8;              // 128
    int*   boff    = bsum + 128;                   // 128
    int*   src_d   = boff + 128;                   // NE
    __half* h16    = (__half*)(src_d + NE);        // NN*64 halfs = 800,000 f

    hipMemsetAsync(d_out, 0, (size_t)NG * NC * sizeof(float), stream);
    hipMemsetAsync(cnt, 0, NN * sizeof(int), stream);

    hist_k<<<(NE + 255) / 256, 256, 0, stream>>>(dst, cnt);
    scan_part_k<<<SCAN_NB, 256, 0, stream>>>(cnt, bsum);
    scan_mid_k<<<1, 128, 0, stream>>>(bsum, boff, dstoff, gids, gcnt);
    scan_final_k<<<SCAN_NB, 256, 0, stream>>>(cnt, boff, dstoff, cur);
    scatter_k<<<(NE + 255) / 256, 256, 0, stream>>>(src, dst, cemb, cur, src_d, dnorm_d);
    cast_h16_k<<<(NN * 16 + 255) / 256, 256, 0, stream>>>(feature, h16);

    const float* h_old = feature;
    float* bufs[2] = {bufX, bufY};
    for (int l = 0; l < 3; l++) {
        float* agg = bufs[l & 1];
        edge_E_k<<<NWE / 4, 256, 0, stream>>>(src_d, dstoff, dnorm_d, h16, E, sums);
        finish_gemm_part_k<<<dim3((NN + 127) / 128, 4), 256, 0, stream>>>(E, W[l], Pparts);
        combine_stats_k<<<512, 256, 0, stream>>>(Pparts, gids, agg, sums, sumsq, Xg);
        if (l < 2) {
            bn_apply_k<<<256, 256, 0, stream>>>(agg, h_old, sums, sumsq, gam[l], bet[l],
                                                agg, h16, l > 0, Xg, gcnt, Pold,
                                                cW1, cb1, cg1, cbt1, cW2, cb2, out);
        } else {
            classifier_only_k<<<1, 256, 0, stream>>>(sums, sumsq, Xg, gcnt, Pold,
                                                     gam[l], bet[l],
                                                     cW1, cb1, cg1, cbt1, cW2, cb2, out);
        }
        h_old = agg;
    }
}